// Round 2
// baseline (260.684 us; speedup 1.0000x reference)
//
#include <hip/hip_runtime.h>
#include <hip/hip_bf16.h>
#include <stdint.h>

typedef unsigned short u16;

#define B_  4
#define LQ  2048
#define LK  4096
#define D_  1024
#define DC  512
#define EPSF 1e-6f

typedef __bf16 bf16x8 __attribute__((ext_vector_type(8)));
typedef float  f32x4  __attribute__((ext_vector_type(4)));

// ---------- helpers ----------
__device__ __forceinline__ u16 f2bf(float f) {
    uint32_t u = __float_as_uint(f);
    uint32_t r = (u + 0x7FFFu + ((u >> 16) & 1u)) >> 16;  // RNE
    return (u16)r;
}
__device__ __forceinline__ float bf2f(u16 h) {
    return __uint_as_float(((uint32_t)h) << 16);
}
__device__ __forceinline__ void gload_lds16(const void* g, void* l) {
    __builtin_amdgcn_global_load_lds(
        (const __attribute__((address_space(1))) uint32_t*)g,
        (__attribute__((address_space(3))) uint32_t*)l, 16, 0, 0);
}

// ---------- prep kernels ----------
// one block per q row: convert to bf16 + row sum of squares (f32 source)
__global__ void prep_q(const float* __restrict__ q, u16* __restrict__ qb,
                       float* __restrict__ qsq) {
    int row = blockIdx.x;                       // 0..B*LQ-1
    const float4 v = reinterpret_cast<const float4*>(q + (size_t)row * D_)[threadIdx.x];
    ushort4 o;
    o.x = f2bf(v.x); o.y = f2bf(v.y); o.z = f2bf(v.z); o.w = f2bf(v.w);
    reinterpret_cast<ushort4*>(qb + (size_t)row * D_)[threadIdx.x] = o;
    float s = v.x * v.x + v.y * v.y + v.z * v.z + v.w * v.w;
    #pragma unroll
    for (int off = 32; off; off >>= 1) s += __shfl_down(s, off);
    __shared__ float red[4];
    if ((threadIdx.x & 63) == 0) red[threadIdx.x >> 6] = s;
    __syncthreads();
    if (threadIdx.x == 0) qsq[row] = red[0] + red[1] + red[2] + red[3];
}

// W -> hi/lo bf16 split
__global__ void prep_w(const float* __restrict__ w, u16* __restrict__ wh,
                       u16* __restrict__ wl) {
    int i = blockIdx.x * blockDim.x + threadIdx.x;   // covers D_*DC/2
    float2 v = reinterpret_cast<const float2*>(w)[i];
    ushort2 h, l;
    h.x = f2bf(v.x); l.x = f2bf(v.x - bf2f(h.x));
    h.y = f2bf(v.y); l.y = f2bf(v.y - bf2f(h.y));
    reinterpret_cast<ushort2*>(wh)[i] = h;
    reinterpret_cast<ushort2*>(wl)[i] = l;
}

// one block per k row: dequantize codes to fp32, then hi/lo bf16 split
__global__ void dequant(const int* __restrict__ kc, const float* __restrict__ scale,
                        const float* __restrict__ zero, u16* __restrict__ oh,
                        u16* __restrict__ ol) {
    int row = blockIdx.x;                       // 0..B*LK-1
    float sc = scale[row], z = zero[row];
    int2 v = reinterpret_cast<const int2*>(kc + (size_t)row * DC)[threadIdx.x];
    float a = sc * ((float)v.x - z);
    float b = sc * ((float)v.y - z);
    ushort2 h, l;
    h.x = f2bf(a); l.x = f2bf(a - bf2f(h.x));
    h.y = f2bf(b); l.y = f2bf(b - bf2f(h.y));
    reinterpret_cast<ushort2*>(oh + (size_t)row * DC)[threadIdx.x] = h;
    reinterpret_cast<ushort2*>(ol + (size_t)row * DC)[threadIdx.x] = l;
}

// ---------- GEMM 1: k = kc @ W^T  (M=B*LK, N=D_, K=DC) ----------
// Split-bf16: acc = Ah*Bh + Ah*Bl + Al*Bh  (fp32-grade result).
// Outputs: bf16 k (for cross GEMM) + per-(ntile,wavecol) row sum-of-squares
// partials computed from the fp32 accumulators (for exact k_sq).
__global__ __launch_bounds__(256, 2) void gemm_dec(const u16* __restrict__ Ah,
                                                   const u16* __restrict__ Al,
                                                   const u16* __restrict__ Bh,
                                                   const u16* __restrict__ Bl,
                                                   u16* __restrict__ C,
                                                   float* __restrict__ part) {
    __shared__ u16 Ash[128 * 32];
    __shared__ u16 Asl[128 * 32];
    __shared__ u16 Bsh[128 * 32];
    __shared__ u16 Bsl[128 * 32];
    const int tid = threadIdx.x;
    const int wid = tid >> 6, lane = tid & 63;
    const int lr = lane & 15, lk = lane >> 4;
    const int wr = wid >> 1, wc = wid & 1;
    const int m0 = blockIdx.x * 128, n0 = blockIdx.y * 128;
    const int K = DC;

    f32x4 acc[4][4] = {};

    const int srow = tid >> 2;           // 0..63
    const int scol = (tid & 3) * 8;      // k offset (elements)
    const size_t gA = (size_t)(m0 + srow) * K + scol;
    const size_t gB = (size_t)(n0 + srow) * K + scol;
    char* ashb = (char*)Ash + (wid << 10);
    char* aslb = (char*)Asl + (wid << 10);
    char* bshb = (char*)Bsh + (wid << 10);
    char* bslb = (char*)Bsl + (wid << 10);

    for (int k0 = 0; k0 < K; k0 += 32) {
        gload_lds16(Ah + gA + k0, ashb);
        gload_lds16(Ah + gA + k0 + (size_t)64 * K, ashb + 4096);
        gload_lds16(Al + gA + k0, aslb);
        gload_lds16(Al + gA + k0 + (size_t)64 * K, aslb + 4096);
        gload_lds16(Bh + gB + k0, bshb);
        gload_lds16(Bh + gB + k0 + (size_t)64 * K, bshb + 4096);
        gload_lds16(Bl + gB + k0, bslb);
        gload_lds16(Bl + gB + k0 + (size_t)64 * K, bslb + 4096);
        __syncthreads();
        bf16x8 afh[4], afl[4], bfh[4], bfl[4];
        #pragma unroll
        for (int i = 0; i < 4; i++) {
            int off = (wr * 64 + i * 16 + lr) * 32 + lk * 8;
            afh[i] = *reinterpret_cast<const bf16x8*>(&Ash[off]);
            afl[i] = *reinterpret_cast<const bf16x8*>(&Asl[off]);
        }
        #pragma unroll
        for (int j = 0; j < 4; j++) {
            int off = (wc * 64 + j * 16 + lr) * 32 + lk * 8;
            bfh[j] = *reinterpret_cast<const bf16x8*>(&Bsh[off]);
            bfl[j] = *reinterpret_cast<const bf16x8*>(&Bsl[off]);
        }
        #pragma unroll
        for (int i = 0; i < 4; i++)
            #pragma unroll
            for (int j = 0; j < 4; j++) {
                acc[i][j] = __builtin_amdgcn_mfma_f32_16x16x32_bf16(afh[i], bfh[j], acc[i][j], 0, 0, 0);
                acc[i][j] = __builtin_amdgcn_mfma_f32_16x16x32_bf16(afh[i], bfl[j], acc[i][j], 0, 0, 0);
                acc[i][j] = __builtin_amdgcn_mfma_f32_16x16x32_bf16(afl[i], bfh[j], acc[i][j], 0, 0, 0);
            }
        __syncthreads();
    }

    // write bf16 k
    #pragma unroll
    for (int i = 0; i < 4; i++) {
        int row = m0 + wr * 64 + i * 16 + lk * 4;
        #pragma unroll
        for (int j = 0; j < 4; j++) {
            int col = n0 + wc * 64 + j * 16 + lr;
            #pragma unroll
            for (int r = 0; r < 4; r++)
                C[(size_t)(row + r) * D_ + col] = f2bf(acc[i][j][r]);
        }
    }
    // fp32 row sum-of-squares partials (deterministic: indexed by ntile*2+wc)
    #pragma unroll
    for (int i = 0; i < 4; i++) {
        #pragma unroll
        for (int r = 0; r < 4; r++) {
            float p = 0.f;
            #pragma unroll
            for (int j = 0; j < 4; j++) { float v = acc[i][j][r]; p += v * v; }
            p += __shfl_xor(p, 1);
            p += __shfl_xor(p, 2);
            p += __shfl_xor(p, 4);
            p += __shfl_xor(p, 8);
            if (lr == 0) {
                int row = m0 + wr * 64 + i * 16 + lk * 4 + r;
                part[(size_t)row * 16 + blockIdx.y * 2 + wc] = p;
            }
        }
    }
}

// sum the 16 partials per row
__global__ void ksq_reduce(const float* __restrict__ part, float* __restrict__ ksq) {
    int row = blockIdx.x * 256 + threadIdx.x;
    const float4* p = reinterpret_cast<const float4*>(part + (size_t)row * 16);
    float s = 0.f;
    #pragma unroll
    for (int i = 0; i < 4; i++) { float4 v = p[i]; s += v.x + v.y + v.z + v.w; }
    ksq[row] = s;
}

// ---------- GEMM 2: cross = q @ k^T + Poincare distance epilogue ----------
__global__ __launch_bounds__(256, 2) void gemm_dist(const u16* __restrict__ Qb,
                                                    const u16* __restrict__ Kb,
                                                    const float* __restrict__ qsq,
                                                    const float* __restrict__ ksq,
                                                    float* __restrict__ out) {
    const int b = blockIdx.z;
    const u16* A  = Qb + (size_t)b * LQ * D_;
    const u16* Bt = Kb + (size_t)b * LK * D_;
    float* O = out + (size_t)b * LQ * LK;
    const float* qs_ = qsq + b * LQ;
    const float* ks_ = ksq + b * LK;

    __shared__ u16 As[128 * 32];
    __shared__ u16 Bs[128 * 32];
    const int tid = threadIdx.x;
    const int wid = tid >> 6, lane = tid & 63;
    const int lr = lane & 15, lk = lane >> 4;
    const int wr = wid >> 1, wc = wid & 1;
    const int m0 = blockIdx.x * 128, n0 = blockIdx.y * 128;
    const int K = D_;

    f32x4 acc[4][4] = {};

    const int srow = tid >> 2;
    const int scol = (tid & 3) * 8;
    const u16* ag = A + (size_t)(m0 + srow) * K + scol;
    const u16* bg = Bt + (size_t)(n0 + srow) * K + scol;
    char* asb = (char*)As + (wid << 10);
    char* bsb = (char*)Bs + (wid << 10);

    for (int k0 = 0; k0 < K; k0 += 32) {
        gload_lds16(ag + k0, asb);
        gload_lds16(ag + k0 + (size_t)64 * K, asb + 4096);
        gload_lds16(bg + k0, bsb);
        gload_lds16(bg + k0 + (size_t)64 * K, bsb + 4096);
        __syncthreads();
        bf16x8 af[4], bfr[4];
        #pragma unroll
        for (int i = 0; i < 4; i++)
            af[i] = *reinterpret_cast<const bf16x8*>(&As[(wr * 64 + i * 16 + lr) * 32 + lk * 8]);
        #pragma unroll
        for (int j = 0; j < 4; j++)
            bfr[j] = *reinterpret_cast<const bf16x8*>(&Bs[(wc * 64 + j * 16 + lr) * 32 + lk * 8]);
        #pragma unroll
        for (int i = 0; i < 4; i++)
            #pragma unroll
            for (int j = 0; j < 4; j++)
                acc[i][j] = __builtin_amdgcn_mfma_f32_16x16x32_bf16(af[i], bfr[j], acc[i][j], 0, 0, 0);
        __syncthreads();
    }

    #pragma unroll
    for (int i = 0; i < 4; i++) {
        int row = m0 + wr * 64 + i * 16 + lk * 4;
        #pragma unroll
        for (int j = 0; j < 4; j++) {
            int col = n0 + wc * 64 + j * 16 + lr;
            float ks = ks_[col];
            float kcl = fminf(ks, 1.f - EPSF);
            #pragma unroll
            for (int r = 0; r < 4; r++) {
                int gr = row + r;
                float qs = qs_[gr];
                float diff = fmaxf(qs + ks - 2.f * acc[i][j][r], 0.f);
                float qcl = fminf(qs, 1.f - EPSF);
                float denom = (1.f - qcl) * (1.f - kcl) + EPSF;
                float u = 2.f * diff / denom;
                // arccosh(1+u) = log1p(u + sqrt(u*(u+2))) — cancellation-free
                O[(size_t)gr * LK + col] = log1pf(u + sqrtf(u * (u + 2.f)));
            }
        }
    }
}

// ---------- launcher ----------
extern "C" void kernel_launch(void* const* d_in, const int* in_sizes, int n_in,
                              void* d_out, int out_size, void* d_ws, size_t ws_size,
                              hipStream_t stream) {
    const float* q      = (const float*)d_in[0];
    const int*   kcmp   = (const int*)d_in[1];
    const float* wup    = (const float*)d_in[2];
    const float* kscale = (const float*)d_in[3];
    const float* kzero  = (const float*)d_in[4];
    float* out = (float*)d_out;

    char* ws = (char*)d_ws;
    u16*   qb   = (u16*)(ws);                        // 16 MiB
    u16*   kb   = (u16*)(ws + 16777216);             // 32 MiB
    u16*   kch  = (u16*)(ws + 50331648);             // 16 MiB
    u16*   kclw = (u16*)(ws + 67108864);             // 16 MiB
    u16*   wh   = (u16*)(ws + 83886080);             // 1 MiB
    u16*   wl   = (u16*)(ws + 84934656);             // 1 MiB
    float* qsq  = (float*)(ws + 85983232);           // 32 KiB
    float* ksq  = (float*)(ws + 86016000);           // 64 KiB
    float* part = (float*)(ws + 86081536);           // 1 MiB (16 partials/row)

    prep_q<<<B_ * LQ, 256, 0, stream>>>(q, qb, qsq);
    prep_w<<<(D_ * DC / 2) / 256, 256, 0, stream>>>(wup, wh, wl);
    dequant<<<B_ * LK, 256, 0, stream>>>(kcmp, kscale, kzero, kch, kclw);

    dim3 g1((B_ * LK) / 128, D_ / 128);              // 128 x 8
    gemm_dec<<<g1, 256, 0, stream>>>(kch, kclw, wh, wl, kb, part);

    ksq_reduce<<<(B_ * LK) / 256, 256, 0, stream>>>(part, ksq);

    dim3 g2(LQ / 128, LK / 128, B_);                 // 16 x 32 x 4
    gemm_dist<<<g2, 256, 0, stream>>>(qb, kb, qsq, ksq, out);
}

// Round 3
// 184.262 us; speedup vs baseline: 1.4148x; 1.4148x over previous
//
#include <hip/hip_runtime.h>
#include <hip/hip_bf16.h>
#include <stdint.h>

typedef unsigned short u16;

#define B_  4
#define LQ  2048
#define LK  4096
#define D_  1024
#define DC  512
#define EPSF 1e-6f

typedef __bf16 bf16x8 __attribute__((ext_vector_type(8)));
typedef float  f32x4  __attribute__((ext_vector_type(4)));

// ---------- helpers ----------
__device__ __forceinline__ u16 f2bf(float f) {
    uint32_t u = __float_as_uint(f);
    uint32_t r = (u + 0x7FFFu + ((u >> 16) & 1u)) >> 16;  // RNE
    return (u16)r;
}
__device__ __forceinline__ float bf2f(u16 h) {
    return __uint_as_float(((uint32_t)h) << 16);
}
__device__ __forceinline__ void gload_lds16(const void* g, void* l) {
    __builtin_amdgcn_global_load_lds(
        (const __attribute__((address_space(1))) uint32_t*)g,
        (__attribute__((address_space(3))) uint32_t*)l, 16, 0, 0);
}

// ---------- prep kernels ----------
__global__ void prep_q(const float* __restrict__ q, u16* __restrict__ qb,
                       float* __restrict__ qsq) {
    int row = blockIdx.x;                       // 0..B*LQ-1
    const float4 v = reinterpret_cast<const float4*>(q + (size_t)row * D_)[threadIdx.x];
    ushort4 o;
    o.x = f2bf(v.x); o.y = f2bf(v.y); o.z = f2bf(v.z); o.w = f2bf(v.w);
    reinterpret_cast<ushort4*>(qb + (size_t)row * D_)[threadIdx.x] = o;
    float s = v.x * v.x + v.y * v.y + v.z * v.z + v.w * v.w;
    #pragma unroll
    for (int off = 32; off; off >>= 1) s += __shfl_down(s, off);
    __shared__ float red[4];
    if ((threadIdx.x & 63) == 0) red[threadIdx.x >> 6] = s;
    __syncthreads();
    if (threadIdx.x == 0) qsq[row] = red[0] + red[1] + red[2] + red[3];
}

// W -> hi/lo bf16 split
__global__ void prep_w(const float* __restrict__ w, u16* __restrict__ wh,
                       u16* __restrict__ wl) {
    int i = blockIdx.x * blockDim.x + threadIdx.x;   // covers D_*DC/2
    float2 v = reinterpret_cast<const float2*>(w)[i];
    ushort2 h, l;
    h.x = f2bf(v.x); l.x = f2bf(v.x - bf2f(h.x));
    h.y = f2bf(v.y); l.y = f2bf(v.y - bf2f(h.y));
    reinterpret_cast<ushort2*>(wh)[i] = h;
    reinterpret_cast<ushort2*>(wl)[i] = l;
}

// one block per k row: dequantize codes to fp32, then hi/lo bf16 split
__global__ void dequant(const int* __restrict__ kc, const float* __restrict__ scale,
                        const float* __restrict__ zero, u16* __restrict__ oh,
                        u16* __restrict__ ol) {
    int row = blockIdx.x;                       // 0..B*LK-1
    float sc = scale[row], z = zero[row];
    int2 v = reinterpret_cast<const int2*>(kc + (size_t)row * DC)[threadIdx.x];
    float a = sc * ((float)v.x - z);
    float b = sc * ((float)v.y - z);
    ushort2 h, l;
    h.x = f2bf(a); l.x = f2bf(a - bf2f(h.x));
    h.y = f2bf(b); l.y = f2bf(b - bf2f(h.y));
    reinterpret_cast<ushort2*>(oh + (size_t)row * DC)[threadIdx.x] = h;
    reinterpret_cast<ushort2*>(ol + (size_t)row * DC)[threadIdx.x] = l;
}

// ---------- GEMM 1: k = kc @ W^T  (M=B*LK, N=D_, K=DC) ----------
// Split-bf16: acc = Ah*Bh + Ah*Bl + Al*Bh  (fp32-grade result).
__global__ __launch_bounds__(256, 2) void gemm_dec(const u16* __restrict__ Ah,
                                                   const u16* __restrict__ Al,
                                                   const u16* __restrict__ Bh,
                                                   const u16* __restrict__ Bl,
                                                   u16* __restrict__ C,
                                                   float* __restrict__ part) {
    __shared__ u16 Ash[128 * 32];
    __shared__ u16 Asl[128 * 32];
    __shared__ u16 Bsh[128 * 32];
    __shared__ u16 Bsl[128 * 32];
    const int tid = threadIdx.x;
    const int wid = tid >> 6, lane = tid & 63;
    const int lr = lane & 15, lk = lane >> 4;
    const int wr = wid >> 1, wc = wid & 1;
    const int m0 = blockIdx.x * 128, n0 = blockIdx.y * 128;
    const int K = DC;

    f32x4 acc[4][4] = {};

    const int srow = tid >> 2;           // 0..63
    const int scol = (tid & 3) * 8;      // k offset (elements)
    const size_t gA = (size_t)(m0 + srow) * K + scol;
    const size_t gB = (size_t)(n0 + srow) * K + scol;
    char* ashb = (char*)Ash + (wid << 10);
    char* aslb = (char*)Asl + (wid << 10);
    char* bshb = (char*)Bsh + (wid << 10);
    char* bslb = (char*)Bsl + (wid << 10);

    for (int k0 = 0; k0 < K; k0 += 32) {
        gload_lds16(Ah + gA + k0, ashb);
        gload_lds16(Ah + gA + k0 + (size_t)64 * K, ashb + 4096);
        gload_lds16(Al + gA + k0, aslb);
        gload_lds16(Al + gA + k0 + (size_t)64 * K, aslb + 4096);
        gload_lds16(Bh + gB + k0, bshb);
        gload_lds16(Bh + gB + k0 + (size_t)64 * K, bshb + 4096);
        gload_lds16(Bl + gB + k0, bslb);
        gload_lds16(Bl + gB + k0 + (size_t)64 * K, bslb + 4096);
        __syncthreads();
        bf16x8 afh[4], afl[4], bfh[4], bfl[4];
        #pragma unroll
        for (int i = 0; i < 4; i++) {
            int off = (wr * 64 + i * 16 + lr) * 32 + lk * 8;
            afh[i] = *reinterpret_cast<const bf16x8*>(&Ash[off]);
            afl[i] = *reinterpret_cast<const bf16x8*>(&Asl[off]);
        }
        #pragma unroll
        for (int j = 0; j < 4; j++) {
            int off = (wc * 64 + j * 16 + lr) * 32 + lk * 8;
            bfh[j] = *reinterpret_cast<const bf16x8*>(&Bsh[off]);
            bfl[j] = *reinterpret_cast<const bf16x8*>(&Bsl[off]);
        }
        #pragma unroll
        for (int i = 0; i < 4; i++)
            #pragma unroll
            for (int j = 0; j < 4; j++) {
                acc[i][j] = __builtin_amdgcn_mfma_f32_16x16x32_bf16(afh[i], bfh[j], acc[i][j], 0, 0, 0);
                acc[i][j] = __builtin_amdgcn_mfma_f32_16x16x32_bf16(afh[i], bfl[j], acc[i][j], 0, 0, 0);
                acc[i][j] = __builtin_amdgcn_mfma_f32_16x16x32_bf16(afl[i], bfh[j], acc[i][j], 0, 0, 0);
            }
        __syncthreads();
    }

    #pragma unroll
    for (int i = 0; i < 4; i++) {
        int row = m0 + wr * 64 + i * 16 + lk * 4;
        #pragma unroll
        for (int j = 0; j < 4; j++) {
            int col = n0 + wc * 64 + j * 16 + lr;
            #pragma unroll
            for (int r = 0; r < 4; r++)
                C[(size_t)(row + r) * D_ + col] = f2bf(acc[i][j][r]);
        }
    }
    #pragma unroll
    for (int i = 0; i < 4; i++) {
        #pragma unroll
        for (int r = 0; r < 4; r++) {
            float p = 0.f;
            #pragma unroll
            for (int j = 0; j < 4; j++) { float v = acc[i][j][r]; p += v * v; }
            p += __shfl_xor(p, 1);
            p += __shfl_xor(p, 2);
            p += __shfl_xor(p, 4);
            p += __shfl_xor(p, 8);
            if (lr == 0) {
                int row = m0 + wr * 64 + i * 16 + lk * 4 + r;
                part[(size_t)row * 16 + blockIdx.y * 2 + wc] = p;
            }
        }
    }
}

// sum the 16 partials per row
__global__ void ksq_reduce(const float* __restrict__ part, float* __restrict__ ksq) {
    int row = blockIdx.x * 256 + threadIdx.x;
    const float4* p = reinterpret_cast<const float4*>(part + (size_t)row * 16);
    float s = 0.f;
    #pragma unroll
    for (int i = 0; i < 4; i++) { float4 v = p[i]; s += v.x + v.y + v.z + v.w; }
    ksq[row] = s;
}

// ---------- GEMM 2: cross = q @ k^T + Poincare distance epilogue ----------
// Single-barrier double-buffered 2-phase K-loop (T3-minimum) + fast-math epilogue.
__global__ __launch_bounds__(256, 2) void gemm_dist(const u16* __restrict__ Qb,
                                                    const u16* __restrict__ Kb,
                                                    const float* __restrict__ qsq,
                                                    const float* __restrict__ ksq,
                                                    float* __restrict__ out) {
    const int b = blockIdx.z;
    const u16* A  = Qb + (size_t)b * LQ * D_;
    const u16* Bt = Kb + (size_t)b * LK * D_;
    float* O = out + (size_t)b * LQ * LK;
    const float* qs_ = qsq + b * LQ;
    const float* ks_ = ksq + b * LK;

    __shared__ u16 As[2][128 * 32];
    __shared__ u16 Bs[2][128 * 32];
    const int tid = threadIdx.x;
    const int wid = tid >> 6, lane = tid & 63;
    const int lr = lane & 15, lk = lane >> 4;
    const int wr = wid >> 1, wc = wid & 1;
    const int m0 = blockIdx.x * 128, n0 = blockIdx.y * 128;
    const int K = D_;
    const int NT = K / 32;                      // 32 K-tiles

    f32x4 acc[4][4] = {};

    const int srow = tid >> 2;
    const int scol = (tid & 3) * 8;
    const u16* ag = A + (size_t)(m0 + srow) * K + scol;
    const u16* bg = Bt + (size_t)(n0 + srow) * K + scol;

    #define STAGE_D(buf, kt) do {                                          \
        char* asb_ = (char*)(&As[(buf)][0]) + (wid << 10);                 \
        char* bsb_ = (char*)(&Bs[(buf)][0]) + (wid << 10);                 \
        int k0_ = (kt) * 32;                                               \
        gload_lds16(ag + k0_, asb_);                                       \
        gload_lds16(ag + k0_ + (size_t)64 * K, asb_ + 4096);               \
        gload_lds16(bg + k0_, bsb_);                                       \
        gload_lds16(bg + k0_ + (size_t)64 * K, bsb_ + 4096);               \
    } while (0)

    #define COMPUTE_D(buf) do {                                            \
        bf16x8 af[4], bfr[4];                                              \
        _Pragma("unroll")                                                  \
        for (int i = 0; i < 4; i++)                                        \
            af[i] = *reinterpret_cast<const bf16x8*>(                      \
                &As[(buf)][(wr * 64 + i * 16 + lr) * 32 + lk * 8]);        \
        _Pragma("unroll")                                                  \
        for (int j = 0; j < 4; j++)                                        \
            bfr[j] = *reinterpret_cast<const bf16x8*>(                     \
                &Bs[(buf)][(wc * 64 + j * 16 + lr) * 32 + lk * 8]);        \
        asm volatile("s_waitcnt lgkmcnt(0)" ::: "memory");                 \
        __builtin_amdgcn_sched_barrier(0);                                 \
        _Pragma("unroll")                                                  \
        for (int i = 0; i < 4; i++)                                        \
            _Pragma("unroll")                                              \
            for (int j = 0; j < 4; j++)                                    \
                acc[i][j] = __builtin_amdgcn_mfma_f32_16x16x32_bf16(       \
                    af[i], bfr[j], acc[i][j], 0, 0, 0);                    \
    } while (0)

    // prologue: stage tile 0
    STAGE_D(0, 0);
    asm volatile("s_waitcnt vmcnt(0)" ::: "memory");
    __builtin_amdgcn_s_barrier();

    int cur = 0;
    for (int t = 0; t < NT - 1; ++t) {
        STAGE_D(cur ^ 1, t + 1);        // issue next-tile loads first
        COMPUTE_D(cur);                 // ds_read + MFMA current tile
        asm volatile("s_waitcnt vmcnt(0)" ::: "memory");
        __builtin_amdgcn_s_barrier();
        cur ^= 1;
    }
    COMPUTE_D(cur);                     // last tile (no stage)

    #undef STAGE_D
    #undef COMPUTE_D

    // ---- fast-math Poincare epilogue ----
    const float LN2 = 0.69314718055994531f;
    float ksv[4], pkv[4];
    #pragma unroll
    for (int j = 0; j < 4; j++) {
        int col = n0 + wc * 64 + j * 16 + lr;
        ksv[j] = ks_[col];
        pkv[j] = 1.f - fminf(ksv[j], 1.f - EPSF);
    }
    #pragma unroll
    for (int i = 0; i < 4; i++) {
        int row = m0 + wr * 64 + i * 16 + lk * 4;
        #pragma unroll
        for (int r = 0; r < 4; r++) {
            int gr = row + r;
            float qs = qs_[gr];
            float pq = 1.f - fminf(qs, 1.f - EPSF);
            float* orow = O + (size_t)gr * LK + n0 + wc * 64 + lr;
            #pragma unroll
            for (int j = 0; j < 4; j++) {
                float d = fmaxf(fmaf(acc[i][j][r], -2.f, qs + ksv[j]), 0.f);
                float den = fmaf(pq, pkv[j], EPSF);
                float u = (d + d) * __builtin_amdgcn_rcpf(den);
                float s = __builtin_amdgcn_sqrtf(u * (u + 2.f));
                orow[j * 16] = LN2 * __builtin_amdgcn_logf(1.f + u + s);
            }
        }
    }
}

// ---------- launcher ----------
extern "C" void kernel_launch(void* const* d_in, const int* in_sizes, int n_in,
                              void* d_out, int out_size, void* d_ws, size_t ws_size,
                              hipStream_t stream) {
    const float* q      = (const float*)d_in[0];
    const int*   kcmp   = (const int*)d_in[1];
    const float* wup    = (const float*)d_in[2];
    const float* kscale = (const float*)d_in[3];
    const float* kzero  = (const float*)d_in[4];
    float* out = (float*)d_out;

    char* ws = (char*)d_ws;
    u16*   qb   = (u16*)(ws);                        // 16 MiB
    u16*   kb   = (u16*)(ws + 16777216);             // 32 MiB
    u16*   kch  = (u16*)(ws + 50331648);             // 16 MiB
    u16*   kclw = (u16*)(ws + 67108864);             // 16 MiB
    u16*   wh   = (u16*)(ws + 83886080);             // 1 MiB
    u16*   wl   = (u16*)(ws + 84934656);             // 1 MiB
    float* qsq  = (float*)(ws + 85983232);           // 32 KiB
    float* ksq  = (float*)(ws + 86016000);           // 64 KiB
    float* part = (float*)(ws + 86081536);           // 1 MiB

    prep_q<<<B_ * LQ, 256, 0, stream>>>(q, qb, qsq);
    prep_w<<<(D_ * DC / 2) / 256, 256, 0, stream>>>(wup, wh, wl);
    dequant<<<B_ * LK, 256, 0, stream>>>(kcmp, kscale, kzero, kch, kclw);

    dim3 g1((B_ * LK) / 128, D_ / 128);              // 128 x 8
    gemm_dec<<<g1, 256, 0, stream>>>(kch, kclw, wh, wl, kb, part);

    ksq_reduce<<<(B_ * LK) / 256, 256, 0, stream>>>(part, ksq);

    dim3 g2(LQ / 128, LK / 128, B_);                 // 16 x 32 x 4
    gemm_dist<<<g2, 256, 0, stream>>>(qb, kb, qsq, ksq, out);
}